// Round 13
// baseline (19773.012 us; speedup 1.0000x reference)
//
#include <hip/hip_runtime.h>
#include <math.h>
#include <stdint.h>

#define B64   64
#define TT    512
#define U400  400
#define G1600 1600
#define NBPL  80            // blocks per layer
#define UPB   5             // units per block (20 gate-columns)
#define NCOL  (4 * UPB)
#define NW    8             // waves per block
#define NTHR  512
#define NBLK  (3 * NBPL)    // 240 blocks -> 1/CU

// ---- device-coherent access helpers (sc1: served at coherence point) ----
__device__ __forceinline__ float ldg_c(const float* p) {
  return __hip_atomic_load(p, __ATOMIC_RELAXED, __HIP_MEMORY_SCOPE_AGENT);
}
__device__ __forceinline__ void stg_c(float* p, float v) {
  __hip_atomic_store(p, v, __ATOMIC_RELAXED, __HIP_MEMORY_SCOPE_AGENT);
}
__device__ __forceinline__ int adl(const unsigned* p) {
  return (int)__hip_atomic_load(p, __ATOMIC_RELAXED, __HIP_MEMORY_SCOPE_AGENT);
}

// x [64][512][3] -> xT [512][3][64]
__global__ void xpose_x_k(const float* __restrict__ x, float* __restrict__ xT) {
  int idx = blockIdx.x * 256 + threadIdx.x;
  if (idx < B64 * TT * 3) {
    int d = idx % 3;
    int t = (idx / 3) % TT;
    int b = idx / (3 * TT);
    xT[(t * 3 + d) * B64 + b] = x[idx];
  }
}

// generic tiled transpose: in R x C -> out C x R
__global__ void transpose_k(const float* __restrict__ in, float* __restrict__ out,
                            int R, int C) {
  __shared__ float tile[32][33];
  int bx = blockIdx.x * 32, by = blockIdx.y * 32;
  int tx = threadIdx.x, ty = threadIdx.y; // block (32,8)
  #pragma unroll
  for (int i = ty; i < 32; i += 8) {
    int r = by + i, c = bx + tx;
    if (r < R && c < C) tile[i][tx] = in[(size_t)r * C + c];
  }
  __syncthreads();
  #pragma unroll
  for (int i = ty; i < 32; i += 8) {
    int r = bx + i, c = by + tx;
    if (r < C && c < R) out[(size_t)r * R + c] = tile[tx][i];
  }
}

// ---- LDS-DMA staging: global -> LDS with sc1 (agent-coherent), no VGPR
// destination. One dwordx4 per lane covers 4 k-rows (1 KB per instruction):
// lane l fetches k = l/16, batches 4(l%16).. ; LDS gets linear [k][batch].
__device__ __forceinline__ void stage_chunk(const float* g, float (*buf)[B64]) {
  #pragma unroll
  for (int j = 0; j < 5; ++j)
    __builtin_amdgcn_global_load_lds(
        (const __attribute__((address_space(1))) void*)(g + j * 4 * B64),
        (__attribute__((address_space(3))) void*)(&buf[4 * j][0]),
        16, 0, 16 /* aux: SC1 -> read at coherence point */);
}

// K-slice GEMM: NCH chunks of 20 k. Double-buffered LDS staging with counted
// vmcnt; chunk c+1 in flight while chunk c is consumed from LDS. Weights are
// scalar reads off wave-uniform pointers (s_load -> SGPR, zero VGPR cost).
template <int NCH>
__device__ __forceinline__ void gemm_lds(const float* __restrict__ aslab, int lane,
                                         float (*stg)[20][B64],   // [2][20][64]
                                         const float* const (&wrow)[NCOL],
                                         float (&acc)[NCOL]) {
  const float* g = aslab + ((lane >> 4) << 6) + ((lane & 15) << 2);
  stage_chunk(g, stg[0]);
  if (NCH > 1) stage_chunk(g + 20 * B64, stg[1]);
  #pragma unroll
  for (int c = 0; c < NCH; ++c) {
    if (c + 1 < NCH) asm volatile("s_waitcnt vmcnt(5)" ::: "memory");
    else             asm volatile("s_waitcnt vmcnt(0)" ::: "memory");
    #pragma unroll
    for (int i = 0; i < 20; ++i) {
      const float a = stg[c & 1][i][lane];
      #pragma unroll
      for (int cc = 0; cc < NCOL; ++cc) acc[cc] += a * wrow[cc][c * 20 + i];
    }
    if (c + 2 < NCH)   // refill the buffer just consumed
      stage_chunk(g + (c + 2) * 20 * B64, stg[c & 1]);
  }
}

struct ScanP {
  const float *xT0, *Wx0;
  const float *WxT1, *WxT2;
  const float *WhT0, *WhT1, *WhT2;
  const float *b0, *b1, *b2;
  const float *pi0, *pi1, *pi2;
  const float *pf0, *pf1, *pf2;
  const float *po0, *po1, *po2;
  float *h0r, *h1r;   // 8-slot h rings [8][400][64]
  float *h2;          // full [512][400][64]
  unsigned *syn;      // counters, 128B-strided
};

#define CNT(l)    (p.syn + (l) * 32)              // published step count, layer l
#define ROOT(l)   (p.syn + (3 + (l)) * 32)        // root arrive accumulator
#define GRP(l, g) (p.syn + (6 + (l) * 8 + (g)) * 32)  // 8 group accumulators/layer

// Persistent LSTM scan (r4 skeleton + LDS-DMA pipelined GEMM + arrive tree).
// grid = 240 (80/layer), block = 512 (8 waves).
// l=0: waves split own-h K=400 as {60x4,40x4}. l>0: waves 0-3 Wx (prev h,
// 4x100), waves 4-7 Wh (own h, 4x100).
__launch_bounds__(NTHR, 1)
__global__ void lstm_scan_k(ScanP p) {
  const int l    = blockIdx.x / NBPL;
  const int u0   = (blockIdx.x % NBPL) * UPB;
  const int grp  = (blockIdx.x % NBPL) / 10;     // arrive group 0..7
  const int lane = threadIdx.x & 63;
  const int kq   = __builtin_amdgcn_readfirstlane(threadIdx.x >> 6); // 0..7

  __shared__ float zs[NW][NCOL][B64];        // 40 KB partials
  __shared__ float stage[NW][2][20][B64];    // 80 KB LDS-DMA double buffers

  const float* WhT  = (l == 0) ? p.WhT0 : (l == 1 ? p.WhT1 : p.WhT2);
  const float* WxT  = (l == 1) ? p.WxT1 : p.WxT2;      // unused for l==0
  const float* bias = (l == 0) ? p.b0  : (l == 1 ? p.b1  : p.b2);
  const float* pi   = (l == 0) ? p.pi0 : (l == 1 ? p.pi1 : p.pi2);
  const float* pf   = (l == 0) ? p.pf0 : (l == 1 ? p.pf1 : p.pf2);
  const float* po   = (l == 0) ? p.po0 : (l == 1 ? p.po1 : p.po2);
  const float* prevb = (l == 1) ? p.h0r : p.h1r;
  float* ownb = (l == 0) ? p.h0r : (l == 1 ? p.h1r : p.h2);
  const int ownmask = (l == 2) ? (TT - 1) : 7;

  // wave's K-slice (wave-uniform; chunks of 20)
  const float* wb; int k0, isH, nch;
  if (l == 0) {
    wb = WhT; isH = 1;
    if (kq < 4) { k0 = kq * 60;             nch = 3; }
    else        { k0 = 240 + (kq - 4) * 40; nch = 2; }
  } else if (kq < 4) {
    wb = WxT; isH = 0; k0 = kq * 100;       nch = 5;
  } else {
    wb = WhT; isH = 1; k0 = (kq - 4) * 100; nch = 5;
  }

  const float* wrow[NCOL];
  #pragma unroll
  for (int g = 0; g < 4; ++g)
    #pragma unroll
    for (int uu = 0; uu < UPB; ++uu)
      wrow[g * UPB + uu] = wb + (size_t)(g * U400 + u0 + uu) * U400 + k0;

  float creg = 0.f;

  for (int t = 0; t < TT; ++t) {
    // ---- wait phase (thread 0 spins on device-coherent counters) ----
    if (threadIdx.x == 0) {
      while (adl(CNT(l)) < t) __builtin_amdgcn_s_sleep(4);
      if (l > 0)
        while (adl(CNT(l - 1)) < t + 1) __builtin_amdgcn_s_sleep(4);
      if (l < 2)
        while (adl(CNT(l + 1)) < t - 7) __builtin_amdgcn_s_sleep(4);
    }
    __syncthreads();

    // ---- GEMM phase: LDS-DMA double-buffered chunks ----
    {
      float acc[NCOL];
      #pragma unroll
      for (int c = 0; c < NCOL; ++c) acc[c] = 0.f;

      if (!(isH && t == 0)) {
        const float* aslab = isH
            ? ownb  + (size_t)((t - 1) & ownmask) * (U400 * B64) + (size_t)k0 * B64
            : prevb + (size_t)(t & 7)             * (U400 * B64) + (size_t)k0 * B64;
        if (nch == 5)      gemm_lds<5>(aslab, lane, stage[kq], wrow, acc);
        else if (nch == 3) gemm_lds<3>(aslab, lane, stage[kq], wrow, acc);
        else               gemm_lds<2>(aslab, lane, stage[kq], wrow, acc);
      }
      #pragma unroll
      for (int c = 0; c < NCOL; ++c) zs[kq][c][lane] = acc[c];
    }
    __syncthreads();   // zs visible to pointwise

    // ---- pointwise phase ----
    if (threadIdx.x < UPB * B64) {
      const int uu = threadIdx.x >> 6;
      const int b  = lane;
      const int u  = u0 + uu;
      float z0 = bias[0 * U400 + u], z1 = bias[1 * U400 + u];
      float z2 = bias[2 * U400 + u], z3 = bias[3 * U400 + u];
      #pragma unroll
      for (int w = 0; w < NW; ++w) {
        z0 += zs[w][0 * UPB + uu][b];
        z1 += zs[w][1 * UPB + uu][b];
        z2 += zs[w][2 * UPB + uu][b];
        z3 += zs[w][3 * UPB + uu][b];
      }
      if (l == 0) {
        #pragma unroll
        for (int dd = 0; dd < 3; ++dd) {
          float xv = p.xT0[(t * 3 + dd) * B64 + b];
          z0 += xv * p.Wx0[dd * G1600 + 0 * U400 + u];
          z1 += xv * p.Wx0[dd * G1600 + 1 * U400 + u];
          z2 += xv * p.Wx0[dd * G1600 + 2 * U400 + u];
          z3 += xv * p.Wx0[dd * G1600 + 3 * U400 + u];
        }
      }
      float cp = creg;
      float ig = 1.f / (1.f + expf(-(z0 + pi[u] * cp)));
      float fg = 1.f / (1.f + expf(-(z1 + pf[u] * cp)));
      float gg = tanhf(z2);
      float cn = fg * cp + ig * gg;
      float og = 1.f / (1.f + expf(-(z3 + po[u] * cn)));
      creg = cn;
      float h = og * tanhf(cn);
      stg_c(&ownb[(size_t)(t & ownmask) * (U400 * B64) + (size_t)u * B64 + b], h);
    }

    // drain: every wave's s_waitcnt vmcnt(0) before s_barrier -> all coherent
    // h-stores acked at the coherence point before the arrive RMW below.
    __syncthreads();

    // ---- two-level arrive tree (monotone accumulators; no resets) ----
    if (threadIdx.x == 0) {
      unsigned go = __hip_atomic_fetch_add(GRP(l, grp), 1u, __ATOMIC_RELAXED,
                                           __HIP_MEMORY_SCOPE_AGENT);
      if (go == (unsigned)((t + 1) * 10 - 1)) {       // last of 10 in group
        unsigned ro = __hip_atomic_fetch_add(ROOT(l), 1u, __ATOMIC_RELAXED,
                                             __HIP_MEMORY_SCOPE_AGENT);
        if (ro == (unsigned)((t + 1) * 8 - 1))        // last group of 8
          __hip_atomic_store(CNT(l), (unsigned)(t + 1), __ATOMIC_RELAXED,
                             __HIP_MEMORY_SCOPE_AGENT);
      }
    }
  }
}

// out[b][t][f] = bd[f] + sum_u h2[t][u][b] * Wd[u][f]
__launch_bounds__(256)
__global__ void dense_k(const float* __restrict__ h2, const float* __restrict__ Wd,
                        const float* __restrict__ bd, float* __restrict__ out) {
  int wid  = blockIdx.x * 4 + (threadIdx.x >> 6);
  int lane = threadIdx.x & 63;
  int t = wid / 3, f = wid - t * 3;
  if (t >= TT) return;
  float acc = bd[f];
  const float* hrow = h2 + (size_t)t * U400 * B64 + lane;
  #pragma unroll 4
  for (int u = 0; u < U400; ++u) acc += hrow[(size_t)u * B64] * Wd[u * 3 + f];
  out[((size_t)lane * TT + t) * 3 + f] = acc;
}

extern "C" void kernel_launch(void* const* d_in, const int* in_sizes, int n_in,
                              void* d_out, int out_size, void* d_ws, size_t ws_size,
                              hipStream_t stream) {
  const float* x   = (const float*)d_in[0];
  const float* Wx0 = (const float*)d_in[1];
  const float* Wh0 = (const float*)d_in[2];
  const float* pi0 = (const float*)d_in[3];
  const float* pf0 = (const float*)d_in[4];
  const float* po0 = (const float*)d_in[5];
  const float* b0  = (const float*)d_in[6];
  const float* Wx1 = (const float*)d_in[7];
  const float* Wh1 = (const float*)d_in[8];
  const float* pi1 = (const float*)d_in[9];
  const float* pf1 = (const float*)d_in[10];
  const float* po1 = (const float*)d_in[11];
  const float* b1  = (const float*)d_in[12];
  const float* Wx2 = (const float*)d_in[13];
  const float* Wh2 = (const float*)d_in[14];
  const float* pi2 = (const float*)d_in[15];
  const float* pf2 = (const float*)d_in[16];
  const float* po2 = (const float*)d_in[17];
  const float* b2  = (const float*)d_in[18];
  const float* Wd  = (const float*)d_in[19];
  const float* bd  = (const float*)d_in[20];

  float* ws   = (float*)d_ws;
  float* xT0  = ws;                  // 98304
  float* WhT0 = xT0  + 98304;        // 640000 each
  float* WhT1 = WhT0 + 640000;
  float* WhT2 = WhT1 + 640000;
  float* WxT1 = WhT2 + 640000;
  float* WxT2 = WxT1 + 640000;
  float* h0r  = WxT2 + 640000;       // 8*400*64 = 204800 each
  float* h1r  = h0r  + 204800;
  float* h2   = h1r  + 204800;       // 13107200
  unsigned* syn = (unsigned*)(h2 + 13107200);  // 30 lines x 128B

  hipMemsetAsync(syn, 0, 30 * 128, stream);

  hipLaunchKernelGGL(xpose_x_k, dim3(384), dim3(256), 0, stream, x, xT0);

  dim3 tb(32, 8);
  dim3 tg((G1600 + 31) / 32, (U400 + 31) / 32);
  hipLaunchKernelGGL(transpose_k, tg, tb, 0, stream, Wh0, WhT0, U400, G1600);
  hipLaunchKernelGGL(transpose_k, tg, tb, 0, stream, Wh1, WhT1, U400, G1600);
  hipLaunchKernelGGL(transpose_k, tg, tb, 0, stream, Wh2, WhT2, U400, G1600);
  hipLaunchKernelGGL(transpose_k, tg, tb, 0, stream, Wx1, WxT1, U400, G1600);
  hipLaunchKernelGGL(transpose_k, tg, tb, 0, stream, Wx2, WxT2, U400, G1600);

  ScanP hp;
  hp.xT0 = xT0;  hp.Wx0 = Wx0;
  hp.WxT1 = WxT1; hp.WxT2 = WxT2;
  hp.WhT0 = WhT0; hp.WhT1 = WhT1; hp.WhT2 = WhT2;
  hp.b0 = b0; hp.b1 = b1; hp.b2 = b2;
  hp.pi0 = pi0; hp.pi1 = pi1; hp.pi2 = pi2;
  hp.pf0 = pf0; hp.pf1 = pf1; hp.pf2 = pf2;
  hp.po0 = po0; hp.po1 = po1; hp.po2 = po2;
  hp.h0r = h0r; hp.h1r = h1r; hp.h2 = h2;
  hp.syn = syn;

  void* args[] = { &hp };
  hipLaunchCooperativeKernel((void*)lstm_scan_k, dim3(NBLK), dim3(NTHR),
                             args, 0, stream);

  hipLaunchKernelGGL(dense_k, dim3(384), dim3(256), 0, stream, h2, Wd, bd,
                     (float*)d_out);
}